// Round 8
// baseline (300.307 us; speedup 1.0000x reference)
//
#include <hip/hip_runtime.h>

#define KTAPS 9
#define DIL 6
#define BN_EPS 1e-5f
#define BB 8
#define CIN 256
#define COUT 256
#define NPTS 8192
#define BN 128
#define BSTRIDE 34   // B row stride in shorts (68 B -> dword stride 17, conflict-free)
#define XW 192       // x window cols (halo 24 each side within XOFF)
#define XPAD 200     // x_win row stride in floats (breaks 192%32==0 conflicts)
#define XOFF 32      // window col 0 = n0 - XOFF
#define NCHUNK 72

typedef __attribute__((ext_vector_type(8))) short short8;
typedef __attribute__((ext_vector_type(4))) float f32x4;

__device__ __forceinline__ unsigned short f2bf(float f) {
  union { float f; unsigned u; } v; v.f = f;
  unsigned r = v.u + 0x7fffu + ((v.u >> 16) & 1u);   // RNE
  return (unsigned short)(r >> 16);
}

// ---------------------------------------------------------------- pre: pack W + zero sums
// Wa layout: [chunk][wave][m][lane][8]  (lane = quad*16 + col)
// element = W[mi = wave*64+m*16+col][c = (chunk&7)*32 + quad*8 + s][ktap = chunk>>3]
__global__ __launch_bounds__(256)
void pre_kernel(const float* __restrict__ W, short* __restrict__ Wa,
                float* __restrict__ sums) {
  int bid = blockIdx.x;
  if (bid < 2304) {
    int idx = bid * 256 + threadIdx.x;
    int s = idx & 7;
    int lane = (idx >> 3) & 63;
    int m = (idx >> 9) & 3;
    int wave = (idx >> 11) & 3;
    int chunk = idx >> 13;
    int c_lane = lane & 15;
    int q = lane >> 4;
    int mi = wave * 64 + m * 16 + c_lane;
    int kk = q * 8 + s;
    int ktap = chunk >> 3;
    int c = ((chunk & 7) << 5) + kk;
    Wa[idx] = (short)f2bf(W[(size_t)mi * (CIN * KTAPS) + c * KTAPS + ktap]);
  } else {
    if (threadIdx.x < 512) sums[threadIdx.x] = 0.f;
  }
}

// ---------------------------------------------------------------- MFMA conv: reg-A, LDS x-window
__global__ __launch_bounds__(256, 2)
void conv_mfma(const float* __restrict__ x, const float* __restrict__ coords,
               const float* __restrict__ rot, const float* __restrict__ dist,
               const short* __restrict__ Wa, const float* __restrict__ bias,
               float* __restrict__ out,
               float* __restrict__ sums1, float* __restrict__ sums2) {
  __shared__ short B_lds[2][BN * BSTRIDE];   // 17.4 KB dbuf [n][kk]
  __shared__ float x_win[32 * XPAD];         // 25.6 KB
  __shared__ float g_lds[KTAPS * BN];        // 4.6 KB

  const int tid = threadIdx.x;
  const int b = blockIdx.y;
  const int n0 = blockIdx.x * BN;
  const int wave = tid >> 6;
  const int lane = tid & 63;
  const int col = lane & 15;
  const int quad = lane >> 4;
  const int tl = tid & 63;          // B-build n index (rows tl, tl+64)
  const int tkk = (tid >> 6) * 8;   // B-build kk base

  // ---- g prologue: tap weights for this block's 128 n, all taps -> LDS
  {
    const float* cb = coords + (size_t)b * 3 * NPTS;
    const float* rb = rot + (size_t)b * 3 * NPTS;
    const float* db = dist + (size_t)b * NPTS;
    for (int t = tid; t < KTAPS * BN; t += 256) {
      int k = t >> 7;
      int n = n0 + (t & 127);
      int j = n + (k - KTAPS / 2) * DIL;
      float gv = 0.f;
      if (j >= 0 && j < NPTS) {
        float c0x = cb[n], c0y = cb[NPTS + n], c0z = cb[2 * NPTS + n];
        float r0x = rb[n], r0y = rb[NPTS + n], r0z = rb[2 * NPTS + n];
        float dcx = c0x - cb[j], dcy = c0y - cb[NPTS + j], dcz = c0z - cb[2 * NPTS + j];
        float dc = dcx * dcx + dcy * dcy + dcz * dcz;
        float dd = db[n] - db[j];
        dd *= dd;
        float gauss = expf(-(dc + dd) * 0.5f);
        float rjx = rb[j], rjy = rb[NPTS + j], rjz = rb[2 * NPTS + j];
        float num = r0x * rjx + r0y * rjy + r0z * rjz;
        float r0n = r0x * r0x + r0y * r0y + r0z * r0z;
        float den = sqrtf(r0n * (rjx * rjx + rjy * rjy + rjz * rjz)) + 1e-8f;
        gv = gauss * fabsf(num / den);
      }
      g_lds[t] = gv;
    }
  }

  const float* xb = x + (size_t)b * CIN * NPTS;
  const int xchl = tid >> 3;        // staging channel 0..31
  const int xc0 = (tid & 7) * 4;    // staging col base
  const short* pAbase = Wa + (size_t)wave * 2048 + (size_t)lane * 8;

  // stage_xwin(c8): 32ch x 192 cols window, padded rows
#define STAGE_XWIN(C8N)                                                     \
  {                                                                         \
    const float* xrow = xb + (size_t)((C8N) * 32 + xchl) * NPTS;            \
    _Pragma("unroll")                                                       \
    for (int q_ = 0; q_ < 6; ++q_) {                                        \
      int cw = xc0 + q_ * 32;                                               \
      int jg = n0 - XOFF + cw;                                              \
      float4 v;                                                             \
      if (jg >= 0 && jg + 3 < NPTS) {                                       \
        v = *(const float4*)&xrow[jg];                                      \
      } else {                                                              \
        float* e = (float*)&v;                                              \
        _Pragma("unroll")                                                   \
        for (int u = 0; u < 4; ++u) {                                       \
          int jj = jg + u;                                                  \
          e[u] = (jj >= 0 && jj < NPTS) ? xrow[jj] : 0.f;                   \
        }                                                                   \
      }                                                                     \
      *(float4*)&x_win[xchl * XPAD + cw] = v;                               \
    }                                                                       \
  }

  // build B tile for tap KB into buffer BUF (reads x_win + g_lds)
#define BUILD_B(BUF, KB)                                                    \
  {                                                                         \
    const int base_ = XOFF + tl + ((KB)-4) * DIL;                           \
    const float g0_ = g_lds[(KB)*BN + tl];                                  \
    const float g1_ = g_lds[(KB)*BN + tl + 64];                             \
    short8 p0_, p1_;                                                        \
    _Pragma("unroll")                                                       \
    for (int cc_ = 0; cc_ < 8; ++cc_) {                                     \
      float v0_ = x_win[(tkk + cc_) * XPAD + base_];                        \
      float v1_ = x_win[(tkk + cc_) * XPAD + base_ + 64];                   \
      p0_[cc_] = (short)f2bf(v0_ * g0_);                                    \
      p1_[cc_] = (short)f2bf(v1_ * g1_);                                    \
    }                                                                       \
    *(short8*)&B_lds[BUF][tl * BSTRIDE + tkk] = p0_;                        \
    *(short8*)&B_lds[BUF][(tl + 64) * BSTRIDE + tkk] = p1_;                 \
  }

  f32x4 acc[4][8];
#pragma unroll
  for (int m = 0; m < 4; ++m)
#pragma unroll
    for (int j = 0; j < 8; ++j) acc[m][j] = (f32x4)0.f;

  short8 af[4];

  // ---- prologue: x window for c8=0, A frags chunk 0, B tap 0
  STAGE_XWIN(0)
  {
    const short* p = pAbase;   // chunk 0
#pragma unroll
    for (int m = 0; m < 4; ++m) af[m] = *(const short8*)(p + m * 512);
  }
  __syncthreads();             // x_win + g_lds ready
  BUILD_B(0, 0)
  __syncthreads();             // B[0] ready

  for (int c8 = 0; c8 < 8; ++c8) {
#pragma unroll
    for (int k = 0; k < KTAPS; ++k) {
      const int cur = (c8 + k) & 1;
      const int nxt = cur ^ 1;
      const bool last = (k == 8) && (c8 == 7);

      // ---- prefetch work for next tap
      if (k < 8) {
        BUILD_B(nxt, k + 1)
      } else if (c8 < 7) {
        STAGE_XWIN(c8 + 1)     // x_win free: last read was pre-barrier(k=7)
      }

      // ---- B fragments (conflict-free b128)
      short8 bfr[8];
#pragma unroll
      for (int j = 0; j < 8; ++j)
        bfr[j] = *(short8*)&B_lds[cur][(j * 16 + col) * BSTRIDE + quad * 8];

      // ---- MFMA, reloading af[m] in place for the next chunk (stays in flight
      //      across the barrier; barrier drains lgkm only — no global_load_lds)
      const int cnext = (k < 8) ? ((k + 1) * 8 + c8) : (c8 + 1);
      const short* pAn = pAbase + (size_t)cnext * 8192;
#pragma unroll
      for (int m = 0; m < 4; ++m) {
        short8 a = af[m];
        if (!last) af[m] = *(const short8*)(pAn + m * 512);
#pragma unroll
        for (int j = 0; j < 8; ++j)
          acc[m][j] = __builtin_amdgcn_mfma_f32_16x16x32_bf16(a, bfr[j], acc[m][j], 0, 0, 0);
      }
      __syncthreads();
    }
    if (c8 < 7) {
      BUILD_B((c8 + 1) & 1, 0)   // tap 0 of next c8 (needs fresh x_win)
      __syncthreads();
    }
  }

  // ---- epilogue: bias, BN partial sums, store
  const int obase = wave * 64;
  float* outp = out + (size_t)b * COUT * NPTS + n0;
#pragma unroll
  for (int m = 0; m < 4; ++m) {
    const int o0 = obase + m * 16 + quad * 4;
    const float4 bv = *(const float4*)&bias[o0];
#pragma unroll
    for (int j = 0; j < 8; ++j) {
      acc[m][j][0] += bv.x; acc[m][j][1] += bv.y;
      acc[m][j][2] += bv.z; acc[m][j][3] += bv.w;
    }
#pragma unroll
    for (int r = 0; r < 4; ++r) {
      float s1 = 0.f, s2 = 0.f;
#pragma unroll
      for (int j = 0; j < 8; ++j) {
        float v = acc[m][j][r];
        s1 += v; s2 += v * v;
      }
      s1 += __shfl_xor(s1, 1); s2 += __shfl_xor(s2, 1);
      s1 += __shfl_xor(s1, 2); s2 += __shfl_xor(s2, 2);
      s1 += __shfl_xor(s1, 4); s2 += __shfl_xor(s2, 4);
      s1 += __shfl_xor(s1, 8); s2 += __shfl_xor(s2, 8);
      if (col == 0) {
        atomicAdd(&sums1[o0 + r], s1);
        atomicAdd(&sums2[o0 + r], s2);
      }
#pragma unroll
      for (int j = 0; j < 8; ++j)
        outp[(size_t)(o0 + r) * NPTS + j * 16 + col] = acc[m][j][r];
    }
  }
}

// ---------------------------------------------------------------- BN + ReLU
__global__ __launch_bounds__(256)
void bn_apply(float* __restrict__ out, const float* __restrict__ sums1,
              const float* __restrict__ sums2, const float* __restrict__ gamma,
              const float* __restrict__ beta) {
  int bo = blockIdx.x;
  int o = bo & (COUT - 1);
  const float inv = 1.f / (float)(BB * NPTS);
  float mean = sums1[o] * inv;
  float var = sums2[o] * inv - mean * mean;
  float scale = gamma[o] * rsqrtf(var + BN_EPS);
  float shift = beta[o] - mean * scale;
  float4* p = (float4*)(out + (size_t)bo * NPTS);
  for (int i = threadIdx.x; i < NPTS / 4; i += blockDim.x) {
    float4 v = p[i];
    v.x = fmaxf(fmaf(v.x, scale, shift), 0.f);
    v.y = fmaxf(fmaf(v.y, scale, shift), 0.f);
    v.z = fmaxf(fmaf(v.z, scale, shift), 0.f);
    v.w = fmaxf(fmaf(v.w, scale, shift), 0.f);
    p[i] = v;
  }
}

// ---------------------------------------------------------------- launch
extern "C" void kernel_launch(void* const* d_in, const int* in_sizes, int n_in,
                              void* d_out, int out_size, void* d_ws, size_t ws_size,
                              hipStream_t stream) {
  const float* x      = (const float*)d_in[0];
  const float* coords = (const float*)d_in[1];
  const float* rot    = (const float*)d_in[2];
  const float* dist   = (const float*)d_in[3];
  const float* W      = (const float*)d_in[4];
  const float* bias   = (const float*)d_in[5];
  const float* gamma  = (const float*)d_in[6];
  const float* beta   = (const float*)d_in[7];
  float* out = (float*)d_out;

  float* ws    = (float*)d_ws;
  float* sums1 = ws;                    // 256
  float* sums2 = ws + 256;              // 256
  short* Wa    = (short*)(ws + 512);    // 72*8192 bf16

  pre_kernel<<<2305, 256, 0, stream>>>(W, Wa, sums1);
  conv_mfma<<<dim3(NPTS / BN, BB), 256, 0, stream>>>(x, coords, rot, dist, Wa, bias, out, sums1, sums2);
  bn_apply<<<BB * COUT, 256, 0, stream>>>(out, sums1, sums2, gamma, beta);
}